// Round 2
// baseline (436.714 us; speedup 1.0000x reference)
//
#include <hip/hip_runtime.h>

// Problem constants: B=4, C=64, O=64, H=W=128, K=3, KK=9, PAD=1
// ws layout (floats):
//   xT   [4][128][128][64]  : offset 0        size 4194304   (NHWC transpose of x)
//   off  [4][128][18][128]  : offset 4194304  size 1179648   (offset conv output)
//   W4   [144][64][4]       : offset 5373952  size 36864     (weight as [kc4][o][j], kc=k*64+c)
//   OWR  [64][9][18]        : offset 5410816  size 10368     (offset_w as [c][tap][o])
// total 5421184 floats = 21.7 MB

// ---------------------------------------------------------------- prep
__global__ void prep_kernel(const float* __restrict__ offset_w, // [18][64][9]
                            const float* __restrict__ weight,   // [64][64][9]
                            float* __restrict__ W4,             // [144][64][4]
                            float* __restrict__ OWR)            // [64][9][18]
{
    int id = blockIdx.x * 256 + threadIdx.x;
    if (id < 36864) {
        int j   = id & 3;
        int o   = (id >> 2) & 63;
        int kc4 = id >> 8;
        int kc  = kc4 * 4 + j;     // kc = k*64 + c
        int k   = kc >> 6;
        int c   = kc & 63;
        W4[id] = weight[(o * 64 + c) * 9 + k];
    }
    int id2 = id - 36864;
    if (id2 >= 0 && id2 < 10368) {
        int o   = id2 % 18;
        int ct  = id2 / 18;        // c*9 + tap
        int tap = ct % 9;
        int c   = ct / 9;
        OWR[id2] = offset_w[(o * 64 + c) * 9 + tap];
    }
}

// ---------------------------------------------------------------- NCHW -> NHWC
__global__ void transpose_kernel(const float* __restrict__ x, float* __restrict__ xT)
{
    __shared__ __align__(16) float lds[128 * 65];
    int bh = blockIdx.x;            // b*128 + h
    int b = bh >> 7, h = bh & 127;
    int t = threadIdx.x;            // 256
    int w = t & 127, chalf = t >> 7;
    for (int i = 0; i < 32; ++i) {
        int c = i * 2 + chalf;
        lds[w * 65 + c] = x[((b * 64 + c) * 128 + h) * 128 + w];
    }
    __syncthreads();
    for (int i = 0; i < 32; ++i) {
        int L = i * 256 + t;
        int ww = L >> 6, c = L & 63;
        xT[((b * 128 + h) * 128 + ww) * 64 + c] = lds[ww * 65 + c];
    }
}

// ---------------------------------------------------------------- offset conv (3x3 SAME, 64->18)
__global__ __launch_bounds__(256) void offconv_kernel(
    const float* __restrict__ x,        // [4][64][128][128] NCHW
    const float* __restrict__ OWR,      // [64][9][18]
    const float* __restrict__ offset_b, // [18]
    float* __restrict__ off)            // [4][128][18][128]
{
    int wg   = blockIdx.x * 4 + (threadIdx.x >> 6);  // 1024 waves total
    int lane = threadIdx.x & 63;
    int row  = wg >> 1;               // b*128 + h
    int b = row >> 7, h = row & 127;
    int w = ((wg & 1) << 6) + lane;

    float acc[18];
#pragma unroll
    for (int o = 0; o < 18; ++o) acc[o] = offset_b[o];

    for (int c = 0; c < 64; ++c) {
        const float* xb = x + ((b * 64 + c) * 128) * 128;
        float v[9];
#pragma unroll
        for (int ky = 0; ky < 3; ++ky) {
            int yy = h + ky - 1;
            bool yok = (yy >= 0) && (yy < 128);
#pragma unroll
            for (int kx = 0; kx < 3; ++kx) {
                int xx = w + kx - 1;
                bool ok = yok && (xx >= 0) && (xx < 128);
                v[ky * 3 + kx] = ok ? xb[yy * 128 + xx] : 0.0f;
            }
        }
        const float* wr = OWR + c * 9 * 18;   // wave-uniform -> s_loads
#pragma unroll
        for (int tap = 0; tap < 9; ++tap) {
#pragma unroll
            for (int o = 0; o < 18; ++o)
                acc[o] = fmaf(v[tap], wr[tap * 18 + o], acc[o]);
        }
    }
#pragma unroll
    for (int o = 0; o < 18; ++o)
        off[((b * 128 + h) * 18 + o) * 128 + w] = acc[o];
}

// ---------------------------------------------------------------- deformable conv main
__global__ __launch_bounds__(256) void deform_kernel(
    const float* __restrict__ xT,   // [4][128][128][64] NHWC
    const float* __restrict__ off,  // [4][128][18][128]
    const float* __restrict__ W4,   // [144][64][4]
    const float* __restrict__ bias, // [64]
    float* __restrict__ out)        // [4][64][128][128] NCHW
{
    __shared__ __align__(16) float sampL[16 * 580];  // [p][kc] padded 576->580
    __shared__ float offL[18 * 16];                  // [o][p]

    int t    = threadIdx.x;
    int wv   = t >> 6;
    int lane = t & 63;
    int pid0 = blockIdx.x << 4;          // 16 pixels per block, same row
    int b   = pid0 >> 14;
    int rem = pid0 & 16383;
    int h = rem >> 7, w0 = rem & 127;

    // 288 offset values, 256 threads -> strided loop (BUG FIX vs r1: was `if (t<288)`)
    for (int i = t; i < 288; i += 256) {
        int o = i >> 4, p = i & 15;
        offL[o * 16 + p] = off[((b * 128 + h) * 18 + o) * 128 + w0 + p];
    }
    __syncthreads();

    // ---- sampling: 144 (pixel,k) pairs, 4 waves, lane = channel
    const float* xbb = xT + ((b * 128) * 128) * 64 + lane;
    for (int i = 0; i < 36; ++i) {
        int pair = i * 4 + wv;
        int p = pair / 9;
        int k = pair - p * 9;
        float offy = offL[(2 * k) * 16 + p];
        float offx = offL[(2 * k + 1) * 16 + p];
        float py = (float)(h - 1 + (k / 3)) + offy;
        float px = (float)(w0 + p - 1 + (k % 3)) + offx;
        float y0f = floorf(py), x0f = floorf(px);
        float wy1 = py - y0f, wx1 = px - x0f;
        float wy0 = 1.0f - wy1, wx0 = 1.0f - wx1;
        int iy0 = (int)y0f, ix0 = (int)x0f;

        bool y0ok = (iy0 >= 0) && (iy0 < 128);
        bool y1ok = (iy0 + 1 >= 0) && (iy0 + 1 < 128);
        bool x0ok = (ix0 >= 0) && (ix0 < 128);
        bool x1ok = (ix0 + 1 >= 0) && (ix0 + 1 < 128);

        float v = 0.0f;
        if (y0ok) {
            const float* r = xbb + iy0 * (128 * 64);
            if (x0ok) v += wy0 * wx0 * r[ix0 * 64];
            if (x1ok) v += wy0 * wx1 * r[(ix0 + 1) * 64];
        }
        if (y1ok) {
            const float* r = xbb + (iy0 + 1) * (128 * 64);
            if (x0ok) v += wy1 * wx0 * r[ix0 * 64];
            if (x1ok) v += wy1 * wx1 * r[(ix0 + 1) * 64];
        }
        sampL[p * 580 + k * 64 + lane] = v;
    }
    __syncthreads();

    // ---- einsum: out[p][o] = sum_kc samp[p][kc] * W[kc][o]
    // wave wv handles pixels wv*4 .. wv*4+3 ; lane = o
    float acc0 = 0.f, acc1 = 0.f, acc2 = 0.f, acc3 = 0.f;
    const float* sp = sampL + (wv * 4) * 580;
    for (int q = 0; q < 144; ++q) {
        float4 wq = *(const float4*)(W4 + (q * 64 + lane) * 4);
        float4 s0 = *(const float4*)(sp + 0 * 580 + q * 4);
        float4 s1 = *(const float4*)(sp + 1 * 580 + q * 4);
        float4 s2 = *(const float4*)(sp + 2 * 580 + q * 4);
        float4 s3 = *(const float4*)(sp + 3 * 580 + q * 4);
        acc0 += s0.x * wq.x + s0.y * wq.y + s0.z * wq.z + s0.w * wq.w;
        acc1 += s1.x * wq.x + s1.y * wq.y + s1.z * wq.z + s1.w * wq.w;
        acc2 += s2.x * wq.x + s2.y * wq.y + s2.z * wq.z + s2.w * wq.w;
        acc3 += s3.x * wq.x + s3.y * wq.y + s3.z * wq.z + s3.w * wq.w;
    }
    float bo = bias[lane];

    __syncthreads();
    // transpose through LDS (reuse sampL) for coalesced NCHW store
    float* outL = sampL;   // [o][p] = [64][16]
    outL[lane * 16 + (wv * 4 + 0)] = acc0 + bo;
    outL[lane * 16 + (wv * 4 + 1)] = acc1 + bo;
    outL[lane * 16 + (wv * 4 + 2)] = acc2 + bo;
    outL[lane * 16 + (wv * 4 + 3)] = acc3 + bo;
    __syncthreads();
#pragma unroll
    for (int i = 0; i < 4; ++i) {
        int idx = i * 256 + t;
        int o = idx >> 4, p = idx & 15;
        out[((b * 64 + o) * 128 + h) * 128 + w0 + p] = outL[o * 16 + p];
    }
}

// ---------------------------------------------------------------- launch
extern "C" void kernel_launch(void* const* d_in, const int* in_sizes, int n_in,
                              void* d_out, int out_size, void* d_ws, size_t ws_size,
                              hipStream_t stream) {
    const float* x        = (const float*)d_in[0];
    const float* offset_w = (const float*)d_in[1];
    const float* offset_b = (const float*)d_in[2];
    const float* weight   = (const float*)d_in[3];
    const float* bias     = (const float*)d_in[4];
    float* ws  = (float*)d_ws;
    float* xT  = ws;
    float* off = ws + 4194304;
    float* W4  = ws + 4194304 + 1179648;
    float* OWR = W4 + 36864;
    float* outp = (float*)d_out;

    hipLaunchKernelGGL(prep_kernel,      dim3(185),  dim3(256), 0, stream, offset_w, weight, W4, OWR);
    hipLaunchKernelGGL(transpose_kernel, dim3(512),  dim3(256), 0, stream, x, xT);
    hipLaunchKernelGGL(offconv_kernel,   dim3(256),  dim3(256), 0, stream, x, OWR, offset_b, off);
    hipLaunchKernelGGL(deform_kernel,    dim3(4096), dim3(256), 0, stream, xT, off, W4, bias, outp);
}

// Round 4
// 132.701 us; speedup vs baseline: 3.2910x; 3.2910x over previous
//
#include <hip/hip_runtime.h>
#include <hip/hip_bf16.h>

// B=4, C=64, O=64, H=W=128, K=3, KK=9, PAD=1
// MFMA 16x16x32 bf16 layouts (guide §3, m89/m120 verified):
//   A[m=lane&15][k=(lane>>4)*8+j]   B[n=lane&15][k=(lane>>4)*8+j]
//   C/D: col(n)=lane&15, row(m)=(lane>>4)*4+reg
//
// ws layout:
//   xT  [4][128][128][64] f32 : float ofs 0         (NHWC transpose of x)
//   off [4][128][18][128] f32 : float ofs 4194304
//   Wb  [4][18][64][8]  bf16  : float ofs 5373952   (deform weight B-frags, otile,s,lane,j)
//   OWb [2][18][64][8]  bf16  : float ofs 5392384   (offset_w B-frags, ntile,s,lane,j)

typedef short short8 __attribute__((ext_vector_type(8)));
typedef float f32x4 __attribute__((ext_vector_type(4)));

// ---------------------------------------------------------------- prep (bf16 B-fragment packing)
__global__ void prep_kernel(const float* __restrict__ offset_w, // [18][64][9]
                            const float* __restrict__ weight,   // [64][64][9]
                            __hip_bfloat16* __restrict__ Wb,    // [4][18][64][8]
                            __hip_bfloat16* __restrict__ OWb)   // [2][18][64][8]
{
    int id = blockIdx.x * 256 + threadIdx.x;
    if (id < 36864) {
        int j    = id & 7;
        int lane = (id >> 3) & 63;
        int id3  = id >> 9;
        int s    = id3 % 18;
        int otile = id3 / 18;
        int n = lane & 15, q = lane >> 4;
        int kap = s * 32 + q * 8 + j;      // kappa = k*64 + c
        int k = kap >> 6, c = kap & 63;
        int o = otile * 16 + n;
        Wb[id] = __float2bfloat16(weight[(o * 64 + c) * 9 + k]);
    }
    int id2 = id - 36864;
    if (id2 >= 0 && id2 < 18432) {
        int j    = id2 & 7;
        int lane = (id2 >> 3) & 63;
        int id3  = id2 >> 9;
        int s    = id3 % 18;
        int ntile = id3 / 18;
        int n = lane & 15, q = lane >> 4;
        int kap = s * 32 + q * 8 + j;
        int k = kap >> 6, c = kap & 63;
        int o = ntile * 16 + n;
        float v = (o < 18) ? offset_w[(o * 64 + c) * 9 + k] : 0.0f;
        OWb[id2] = __float2bfloat16(v);
    }
}

// ---------------------------------------------------------------- NCHW -> NHWC (unchanged, passed)
__global__ void transpose_kernel(const float* __restrict__ x, float* __restrict__ xT)
{
    __shared__ __align__(16) float lds[128 * 65];
    int bh = blockIdx.x;
    int b = bh >> 7, h = bh & 127;
    int t = threadIdx.x;
    int w = t & 127, chalf = t >> 7;
    for (int i = 0; i < 32; ++i) {
        int c = i * 2 + chalf;
        lds[w * 65 + c] = x[((b * 64 + c) * 128 + h) * 128 + w];
    }
    __syncthreads();
    for (int i = 0; i < 32; ++i) {
        int L = i * 256 + t;
        int ww = L >> 6, c = L & 63;
        xT[((b * 128 + h) * 128 + ww) * 64 + c] = lds[ww * 65 + c];
    }
}

// ---------------------------------------------------------------- offset conv via MFMA
// block = 32 pixels of one row; waves: (mtile = wv>>1) x (ntile = wv&1)
__global__ __launch_bounds__(256) void offconv_kernel(
    const float* __restrict__ xT,        // [4][128][128][64] NHWC
    const __hip_bfloat16* __restrict__ OWb, // [2][18][64][8]
    const float* __restrict__ offset_b,  // [18]
    float* __restrict__ off)             // [4][128][18][128]
{
    __shared__ __align__(16) __hip_bfloat16 R[3 * 34 * 72];  // [ky][col][c], col stride 72 (bank pad)

    int t = threadIdx.x, wv = t >> 6, lane = t & 63;
    int pid0 = blockIdx.x << 5;          // 32 pixels
    int b = pid0 >> 14;
    int rem = pid0 & 16383;
    int h = rem >> 7, w0 = rem & 127;

    // stage 3 rows x 34 cols x 64 ch (zero-padded at borders), fp32 -> bf16
    for (int e = t; e < 3 * 34 * 64; e += 256) {
        int c = e & 63, ci = e >> 6;
        int col = ci % 34, ky = ci / 34;
        int hh = h + ky - 1;
        int wwp = w0 + col - 1;
        float v = (hh >= 0 && hh < 128 && wwp >= 0 && wwp < 128)
                    ? xT[((b * 128 + hh) * 128 + wwp) * 64 + c] : 0.0f;
        R[(ky * 34 + col) * 72 + c] = __float2bfloat16(v);
    }
    __syncthreads();

    int mtile = wv >> 1, ntile = wv & 1;
    int n = lane & 15, q = lane >> 4;
    const short8* Bw = (const short8*)OWb + (ntile * 18) * 64 + lane;

    f32x4 acc = {0.f, 0.f, 0.f, 0.f};
#pragma unroll
    for (int s = 0; s < 18; ++s) {
        int k = s >> 1;
        int ky = k / 3, kx = k % 3;
        int col = mtile * 16 + n + kx;
        const short8 a = *(const short8*)&R[(ky * 34 + col) * 72 + (s & 1) * 32 + q * 8];
        const short8 bf = Bw[s * 64];
        acc = __builtin_amdgcn_mfma_f32_16x16x32_bf16(a, bf, acc, 0, 0, 0);
    }
    int o = ntile * 16 + n;
    if (o < 18) {
        float bo = offset_b[o];
        float4 st = {acc[0] + bo, acc[1] + bo, acc[2] + bo, acc[3] + bo};
        *(float4*)&off[((b * 128 + h) * 18 + o) * 128 + w0 + mtile * 16 + q * 4] = st;
    }
}

// ---------------------------------------------------------------- deformable conv main (sample + MFMA einsum)
// block = 16 pixels of one row; 4 waves; grid MUST be 65536/16 = 4096
__global__ __launch_bounds__(256) void deform_kernel(
    const float* __restrict__ xT,   // [4][128][128][64] NHWC
    const float* __restrict__ off,  // [4][128][18][128]
    const __hip_bfloat16* __restrict__ Wb, // [4][18][64][8]
    const float* __restrict__ bias, // [64]
    float* __restrict__ out)        // [4][64][128][128] NCHW
{
    __shared__ float offL[288];                       // [o][p]
    __shared__ __align__(16) int   PCo[144][4];       // clamped corner element-offsets
    __shared__ __align__(16) float PCw[144][4];       // masked bilinear weights
    __shared__ __align__(16) __hip_bfloat16 sampB[18 * 16 * 40]; // [s][p][40], 32 used

    int t = threadIdx.x, wv = t >> 6, lane = t & 63;
    int pid0 = blockIdx.x << 4;
    int b = pid0 >> 14;
    int rem = pid0 & 16383;
    int h = rem >> 7, w0 = rem & 127;

    for (int i = t; i < 288; i += 256) {   // i = o*16 + p
        offL[i] = off[((b * 128 + h) * 18 + (i >> 4)) * 128 + w0 + (i & 15)];
    }
    __syncthreads();

    // per-(pixel,tap) precompute: weights (validity-masked) + clamped corner offsets
    if (t < 144) {
        int p = t / 9, k = t - p * 9;
        float offy = offL[(2 * k) * 16 + p];
        float offx = offL[(2 * k + 1) * 16 + p];
        float py = (float)(h - 1 + (k / 3)) + offy;
        float px = (float)(w0 + p - 1 + (k % 3)) + offx;
        float y0f = floorf(py), x0f = floorf(px);
        float wy1 = py - y0f, wx1 = px - x0f;
        float wy0 = 1.0f - wy1, wx0 = 1.0f - wx1;
        int iy = (int)y0f, ix = (int)x0f;
        bool y0v = (iy >= 0) && (iy < 128);
        bool y1v = (iy >= -1) && (iy < 127);
        bool x0v = (ix >= 0) && (ix < 128);
        bool x1v = (ix >= -1) && (ix < 127);
        int iy0c = min(max(iy, 0), 127), iy1c = min(max(iy + 1, 0), 127);
        int ix0c = min(max(ix, 0), 127), ix1c = min(max(ix + 1, 0), 127);
        PCo[t][0] = (iy0c * 128 + ix0c) * 64;
        PCo[t][1] = (iy0c * 128 + ix1c) * 64;
        PCo[t][2] = (iy1c * 128 + ix0c) * 64;
        PCo[t][3] = (iy1c * 128 + ix1c) * 64;
        PCw[t][0] = (y0v && x0v) ? wy0 * wx0 : 0.0f;
        PCw[t][1] = (y0v && x1v) ? wy0 * wx1 : 0.0f;
        PCw[t][2] = (y1v && x0v) ? wy1 * wx0 : 0.0f;
        PCw[t][3] = (y1v && x1v) ? wy1 * wx1 : 0.0f;
    }
    __syncthreads();

    // sampling: 144 (p,k) pairs / 4 waves; lane = channel
    const float* xb = xT + b * (128 * 128 * 64) + lane;
#pragma unroll 4
    for (int i = 0; i < 36; ++i) {
        int pair = i * 4 + wv;
        int p = pair / 9, k = pair - p * 9;
        int4 ofs = *(const int4*)&PCo[pair][0];
        float4 ww = *(const float4*)&PCw[pair][0];
        float v = ww.x * xb[ofs.x];
        v = fmaf(ww.y, xb[ofs.y], v);
        v = fmaf(ww.z, xb[ofs.z], v);
        v = fmaf(ww.w, xb[ofs.w], v);
        int s = 2 * k + (lane >> 5);
        sampB[(s * 16 + p) * 40 + (lane & 31)] = __float2bfloat16(v);
    }
    __syncthreads();

    // einsum via MFMA: wave wv = o-tile; 18 K-steps
    int n = lane & 15, q = lane >> 4;
    int arow = n * 40 + q * 8;            // p = n slot in A-frag (m index), k-group = q
    const short8* BwW = (const short8*)Wb + (wv * 18) * 64 + lane;
    f32x4 acc = {0.f, 0.f, 0.f, 0.f};
#pragma unroll
    for (int s = 0; s < 18; ++s) {
        const short8 a = *(const short8*)&sampB[s * 640 + arow];
        const short8 bf = BwW[s * 64];
        acc = __builtin_amdgcn_mfma_f32_16x16x32_bf16(a, bf, acc, 0, 0, 0);
    }
    int o = wv * 16 + n;
    float bo = bias[o];
    float4 st = {acc[0] + bo, acc[1] + bo, acc[2] + bo, acc[3] + bo};
    *(float4*)&out[((b * 64 + o) * 128 + h) * 128 + w0 + q * 4] = st;
}

// ---------------------------------------------------------------- launch
extern "C" void kernel_launch(void* const* d_in, const int* in_sizes, int n_in,
                              void* d_out, int out_size, void* d_ws, size_t ws_size,
                              hipStream_t stream) {
    const float* x        = (const float*)d_in[0];
    const float* offset_w = (const float*)d_in[1];
    const float* offset_b = (const float*)d_in[2];
    const float* weight   = (const float*)d_in[3];
    const float* bias     = (const float*)d_in[4];
    float* ws  = (float*)d_ws;
    float* xT  = ws;
    float* off = ws + 4194304;
    __hip_bfloat16* Wb  = (__hip_bfloat16*)(ws + 5373952);
    __hip_bfloat16* OWb = (__hip_bfloat16*)(ws + 5392384);
    float* outp = (float*)d_out;

    hipLaunchKernelGGL(prep_kernel,      dim3(216),  dim3(256), 0, stream, offset_w, weight, Wb, OWb);
    hipLaunchKernelGGL(transpose_kernel, dim3(512),  dim3(256), 0, stream, x, xT);
    hipLaunchKernelGGL(offconv_kernel,   dim3(2048), dim3(256), 0, stream, xT, OWb, offset_b, off);
    hipLaunchKernelGGL(deform_kernel,    dim3(4096), dim3(256), 0, stream, xT, off, Wb, bias, outp);
}